// Round 6
// baseline (97.149 us; speedup 1.0000x reference)
//
#include <hip/hip_runtime.h>
#include <stdint.h>

#define NROWS 8192
#define HALF_N 4096
#define DIM 512          /* elements per row; == bytes per row in fp8 */
#define INV_TEMP 2.0f
#define E2SCALE 2.8853900817779268f  /* INV_TEMP * log2(e) */
#define LN2 0.6931471805599453f
#define NTILES 1056      /* 256x128 tiles, {(tm,tn): tn>=2tm, tm<32, tn<64} */
#define NXCD 8
#define TPX (NTILES / NXCD)  /* 132; NTILES % 8 == 0 -> bijective XCD swizzle */

typedef int i32x8 __attribute__((ext_vector_type(8)));
typedef float f32x16 __attribute__((ext_vector_type(16)));

// global -> LDS direct copy, 16B per lane; LDS dest is wave-uniform base + lane*16
__device__ __forceinline__ void gload_lds16(const unsigned char* g, unsigned char* l) {
  __builtin_amdgcn_global_load_lds(
      (const __attribute__((address_space(1))) unsigned int*)(uintptr_t)g,
      (__attribute__((address_space(3))) unsigned int*)(uint32_t)(uintptr_t)l,
      16, 0, 0);
}

// One wave per row: sumsq -> rsqrt -> fp8 e4m3 store (4 MB). Zeroes sumexp.
__global__ void __launch_bounds__(256) k_normalize(const float* __restrict__ zi,
                                                   const float* __restrict__ zj,
                                                   unsigned char* __restrict__ zn,
                                                   float* __restrict__ sumexp) {
  int tid = threadIdx.x;
  int gid = blockIdx.x * 256 + tid;
  if (gid < NROWS) sumexp[gid] = 0.0f;
  int wave = tid >> 6, lane = tid & 63;
  int row = blockIdx.x * 4 + wave;
  const float* src = (row < HALF_N) ? (zi + (size_t)row * DIM)
                                    : (zj + (size_t)(row - HALF_N) * DIM);
  const float4* s4 = (const float4*)src;
  float4 a = s4[lane];        // cols 4*lane .. +3
  float4 b = s4[lane + 64];   // cols 256+4*lane .. +3
  float ss = a.x * a.x + a.y * a.y + a.z * a.z + a.w * a.w +
             b.x * b.x + b.y * b.y + b.z * b.z + b.w * b.w;
#pragma unroll
  for (int off = 32; off > 0; off >>= 1) ss += __shfl_xor(ss, off, 64);
  float inv = 1.0f / fmaxf(sqrtf(ss), 1e-8f);
  int w0 = __builtin_amdgcn_cvt_pk_fp8_f32(a.x * inv, a.y * inv, 0, false);
  w0 = __builtin_amdgcn_cvt_pk_fp8_f32(a.z * inv, a.w * inv, w0, true);
  int w1 = __builtin_amdgcn_cvt_pk_fp8_f32(b.x * inv, b.y * inv, 0, false);
  w1 = __builtin_amdgcn_cvt_pk_fp8_f32(b.z * inv, b.w * inv, w1, true);
  unsigned char* dst = zn + (size_t)row * DIM;
  *((int*)(dst + lane * 4)) = w0;
  *((int*)(dst + 256 + lane * 4)) = w1;
}

// R6: 256x128 tiles, 4 waves (wave = 128x64 region, acc[4][2] = 4x2 register blocking).
// Rationale (LDS-BW model): R2's 2x2 blocking reads 2 KB LDS per MFMA -> 144 KB/CU per
// window-round ~= the whole window time; LDS bandwidth, not latency, was the ceiling
// (explains R3/R5 nulls). 4x2 halves LDS bytes per MFMA: per CU (2 blocks) 144 KB per
// window of 2x the MFMA content -> LDS 1125 cy vs MFMA 1104 cy/SIMD, balanced.
// Tile set {(tm,tn): tn >= 2tm} with the keep-rule "cell contributes iff gr < gc"
// (adds to rowsum[gr] AND rowsum[gc]) -> every unordered pair counted exactly once;
// no diagonal masking needed; below-diag sub-blocks of straddle tiles are discarded.
__global__ void __launch_bounds__(256, 2) k_simsum(const unsigned char* __restrict__ zn,
                                                   float* __restrict__ sumexp,
                                                   float* __restrict__ posv) {
  __shared__ __align__(16) unsigned char As[3][256 * 64];  // 3 x 16 KB
  __shared__ __align__(16) unsigned char Bs[3][128 * 64];  // 3 x 8 KB
  int tid = threadIdx.x;
  int wave = tid >> 6, lane = tid & 63;

  // XCD-bijective swizzle; tm-major ordering -> consecutive idx share the A-panel.
  int b = blockIdx.x;
  int idx = (b & (NXCD - 1)) * TPX + (b >> 3);
  // decode idx = tm*(63-tm) + tn, tn in [2tm, 64)
  int tm = (int)((65.0f - sqrtf(4225.0f - 4.0f * idx)) * 0.5f);
  while (tm * (65 - tm) > idx) tm--;
  while ((tm + 1) * (64 - tm) <= idx) tm++;
  int tn = idx - tm * (63 - tm);
  int rowBase = tm * 256, colBase = tn * 128;

  int wr = (wave >> 1) * 128, wc = (wave & 1) * 64;  // wave's 128x64 region
  int h = lane >> 5, c32 = lane & 31;                // k-half and row/col within 32-block

  // staging: wave stages 64 rows of A (4 groups of 16) and 32 rows of B (2 groups).
  // 16B/lane; 4 lanes per 64-B row. Granule p of row r holds k-chunk p ^ ((r>>1)&3)
  // (swizzle constant across +16-row groups since (16>>1)&3 == 0 mod 4 pattern).
  int rA = wave * 64 + (lane >> 2);
  int cA = (lane & 3) ^ ((rA >> 1) & 3);
  const unsigned char* gA = zn + (size_t)(rowBase + rA) * DIM + cA * 16;
  int rB = wave * 32 + (lane >> 2);
  int cB = (lane & 3) ^ ((rB >> 1) & 3);
  const unsigned char* gB = zn + (size_t)(colBase + rB) * DIM + cB * 16;

#define STAGE(bf)                                     \
  do {                                                \
    unsigned char* la = &As[bf][wave * 4096];         \
    unsigned char* lb = &Bs[bf][wave * 2048];         \
    gload_lds16(gA, la);                              \
    gload_lds16(gA + 16 * DIM, la + 1024);            \
    gload_lds16(gA + 32 * DIM, la + 2048);            \
    gload_lds16(gA + 48 * DIM, la + 3072);            \
    gload_lds16(gB, lb);                              \
    gload_lds16(gB + 16 * DIM, lb + 1024);            \
    gA += 64; gB += 64;                               \
  } while (0)

  f32x16 acc[4][2];
#pragma unroll
  for (int i = 0; i < 4; i++)
#pragma unroll
    for (int j = 0; j < 2; j++)
#pragma unroll
      for (int r = 0; r < 16; r++) acc[i][j][r] = 0.f;

  // Fragment read indices (int4 = one 16-B granule; row r at granule r*4).
  // Lane (c32,h) needs row-bytes k = h*32 + 0..31 -> granules 2h, 2h+1, XOR-swizzled;
  // sg = ((row>>1)&3) == ((c32>>1)&3) since row = 32k + c32.
  int sg = (c32 >> 1) & 3;
  int p0 = (2 * h) ^ sg, p1 = p0 ^ 1;
  int aIdx[4] = {(wr + c32) * 4, (wr + 32 + c32) * 4,
                 (wr + 64 + c32) * 4, (wr + 96 + c32) * 4};
  int bIdx[2] = {(wc + c32) * 4, (wc + 32 + c32) * 4};

#define COMPUTE(bf)                                                                  \
  do {                                                                               \
    const int4* Av = (const int4*)As[bf];                                            \
    const int4* Bv = (const int4*)Bs[bf];                                            \
    i32x8 af[4], bfr[2];                                                             \
    _Pragma("unroll") for (int i = 0; i < 4; i++) {                                  \
      int4 lo = Av[aIdx[i] + p0], hi = Av[aIdx[i] + p1];                             \
      af[i] = (i32x8){lo.x, lo.y, lo.z, lo.w, hi.x, hi.y, hi.z, hi.w};               \
    }                                                                                \
    _Pragma("unroll") for (int j = 0; j < 2; j++) {                                  \
      int4 lo = Bv[bIdx[j] + p0], hi = Bv[bIdx[j] + p1];                             \
      bfr[j] = (i32x8){lo.x, lo.y, lo.z, lo.w, hi.x, hi.y, hi.z, hi.w};              \
    }                                                                                \
    __builtin_amdgcn_s_setprio(1);                                                   \
    _Pragma("unroll") for (int i = 0; i < 4; i++)                                    \
      _Pragma("unroll") for (int j = 0; j < 2; j++)                                  \
        acc[i][j] = __builtin_amdgcn_mfma_scale_f32_32x32x64_f8f6f4(                 \
            af[i], bfr[j], acc[i][j], 0, 0, /*fp8,fp8*/                              \
            0, 0x7F, 0, 0x7F);            /* scales = 2^0 */                         \
    __builtin_amdgcn_s_setprio(0);                                                   \
  } while (0)

  // ---- K loop: 3 buffers, depth-2 prefetch, counted vmcnt (R2's proven ladder). ----
  // 6 loads/thread/window. At iter-s entry outstanding = w_s(6)+w_{s+1}(6); vmcnt(6)
  // completes w_s while w_{s+1} stays in flight. STAGE(w_{s+2}) overwrites w_{s-1},
  // whose readers drained lgkmcnt before this iter's barrier.
#define ASM_VMCNT(n) asm volatile("s_waitcnt vmcnt(" #n ")" ::: "memory")
#define WINDOW(s, vm)                                        \
  do {                                                       \
    ASM_VMCNT(vm);                                           \
    asm volatile("s_waitcnt lgkmcnt(0)" ::: "memory");       \
    __builtin_amdgcn_sched_barrier(0);                       \
    __builtin_amdgcn_s_barrier();                            \
    __builtin_amdgcn_sched_barrier(0);                       \
    if ((s) + 2 < 8) STAGE(((s) + 2) % 3);                   \
    COMPUTE((s) % 3);                                        \
  } while (0)

  STAGE(0);  // w0
  STAGE(1);  // w1
  WINDOW(0, 6);
  WINDOW(1, 6);
  WINDOW(2, 6);
  WINDOW(3, 6);
  WINDOW(4, 6);
  WINDOW(5, 6);
  WINDOW(6, 6);
  WINDOW(7, 0);

  // ---- Epilogue. 32x32 C/D layout: col = lane&31, row = (reg&3)+8*(reg>>2)+4*h. ----
  // Block (i,j) covers rows rb = rowBase+wr+i*32, cols cb = colBase+wc+j*32.
  // d = cb - rb (wave-uniform, multiple of 32, or 4096/4096±... for pos tiles):
  //   d > 0  : fully above diagonal -> all cells contribute
  //   d == 0 : on-diagonal square -> contribute iff rowIn32 < c32 (strict upper)
  //   d < 0  : below diagonal -> discard (mirror cell computed elsewhere)
  //   d == HALF_N : positives block (above-diag, also extract posv at rowIn==colIn)
  int dbase = colBase + wc - rowBase - wr;  // d(i,j) = dbase + j*32 - i*32
  int rsel = (c32 & 3) | ((c32 >> 3) << 2); // reg with rowIn32 == c32
  bool diagLane = (h == ((c32 >> 2) & 1));  // lane holding rowIn32==c32 elems

  // positives first (acc is overwritten in place below)
#pragma unroll
  for (int i = 0; i < 4; i++)
#pragma unroll
    for (int j = 0; j < 2; j++) {
      int d = dbase + j * 32 - i * 32;
      if (d == HALF_N && diagLane) {
        float sv = acc[i][j][rsel] * INV_TEMP;
        int gr = rowBase + wr + i * 32 + c32;
        posv[gr] = sv;            // unique row across grid -> race-free plain store
        posv[gr + HALF_N] = sv;   // sim symmetric
      }
    }

  // exp2 + keep-rule + partials IN PLACE: acc[i][0][r] <- e0+e1; cp[j] = col partials.
  float cp[2] = {0.f, 0.f};
#pragma unroll
  for (int i = 0; i < 4; i++) {
    int d0 = dbase - i * 32;
    int d1 = d0 + 32;
#pragma unroll
    for (int r = 0; r < 16; r++) {
      int rowIn = (r & 3) + 8 * (r >> 2) + 4 * h;
      float e0 = __builtin_amdgcn_exp2f(acc[i][0][r] * E2SCALE);
      float e1 = __builtin_amdgcn_exp2f(acc[i][1][r] * E2SCALE);
      bool k0 = (d0 > 0) || ((d0 == 0) && (rowIn < c32));
      bool k1 = (d1 > 0) || ((d1 == 0) && (rowIn < c32));
      e0 = k0 ? e0 : 0.f;
      e1 = k1 ? e1 : 0.f;
      cp[0] += e0;
      cp[1] += e1;
      acc[i][0][r] = e0 + e1;
    }
  }

  // Fold-reduce 32 row-partials across the 32-lane half; lane ends with value for
  // index c32 -> (i = c32>>4 within the pair, reg = c32&15).
#define FOLD5(RPX)                                                 \
  do {                                                             \
    _Pragma("unroll") for (int t = 0; t < 16; t++) {               \
      float mine = (lane & 16) ? RPX(t + 16) : RPX(t);             \
      float oth = __shfl_xor((lane & 16) ? RPX(t) : RPX(t + 16), 16, 64); \
      RPX(t) = mine + oth;                                         \
    }                                                              \
    _Pragma("unroll") for (int t = 0; t < 8; t++) {                \
      float mine = (lane & 8) ? RPX(t + 8) : RPX(t);               \
      float oth = __shfl_xor((lane & 8) ? RPX(t) : RPX(t + 8), 8, 64); \
      RPX(t) = mine + oth;                                         \
    }                                                              \
    _Pragma("unroll") for (int t = 0; t < 4; t++) {                \
      float mine = (lane & 4) ? RPX(t + 4) : RPX(t);               \
      float oth = __shfl_xor((lane & 4) ? RPX(t) : RPX(t + 4), 4, 64); \
      RPX(t) = mine + oth;                                         \
    }                                                              \
    _Pragma("unroll") for (int t = 0; t < 2; t++) {                \
      float mine = (lane & 2) ? RPX(t + 2) : RPX(t);               \
      float oth = __shfl_xor((lane & 2) ? RPX(t) : RPX(t + 2), 2, 64); \
      RPX(t) = mine + oth;                                         \
    }                                                              \
    {                                                              \
      float mine = (lane & 1) ? RPX(1) : RPX(0);                   \
      float oth = __shfl_xor((lane & 1) ? RPX(0) : RPX(1), 1, 64); \
      RPX(0) = mine + oth;                                         \
    }                                                              \
  } while (0)

#define RPA(t) acc[(t) >> 4][0][(t) & 15]
#define RPB(t) acc[2 + ((t) >> 4)][0][(t) & 15]
  // lane's row: (c32&3) + 8*((c32>>2)&3) + 4*h within 32; block 32*(c32>>4).
  int myrow = rowBase + wr + 32 * (c32 >> 4) + (c32 & 3) + 8 * ((c32 >> 2) & 3) + 4 * h;
  FOLD5(RPA);                               // i-tiles 0,1: rows wr .. wr+63
  atomicAdd(&sumexp[myrow], RPA(0));
  FOLD5(RPB);                               // i-tiles 2,3: rows wr+64 .. wr+127
  atomicAdd(&sumexp[myrow + 64], RPB(0));
#undef RPA
#undef RPB

  // col sums (mirror contributions of kept cells): combine k-halves, lane-half h
  // picks col-block j=h. Discarded blocks contribute exact zeros.
  cp[0] += __shfl_xor(cp[0], 32, 64);
  cp[1] += __shfl_xor(cp[1], 32, 64);
  float cv = h ? cp[1] : cp[0];
  atomicAdd(&sumexp[colBase + wc + h * 32 + c32], cv);
#undef STAGE
#undef COMPUTE
#undef WINDOW
#undef ASM_VMCNT
#undef FOLD5
}

__global__ void __launch_bounds__(1024) k_final(const float* __restrict__ sumexp,
                                                const float* __restrict__ posv,
                                                float* __restrict__ out) {
  __shared__ float red[16];
  int tid = threadIdx.x;
  const float4* se4 = (const float4*)sumexp;
  const float4* pv4 = (const float4*)posv;
  float p = 0.f;
#pragma unroll
  for (int c = 0; c < 2; c++) {
    float4 se = se4[tid * 2 + c];
    float4 pv = pv4[tid * 2 + c];
    p += (__builtin_amdgcn_logf(se.x) + __builtin_amdgcn_logf(se.y) +
          __builtin_amdgcn_logf(se.z) + __builtin_amdgcn_logf(se.w)) * LN2 -
         (pv.x + pv.y + pv.z + pv.w);
  }
#pragma unroll
  for (int off = 32; off > 0; off >>= 1) p += __shfl_xor(p, off, 64);
  int wv = tid >> 6, ln = tid & 63;
  if (ln == 0) red[wv] = p;
  __syncthreads();
  if (tid == 0) {
    float t = 0.f;
    for (int w = 0; w < 16; w++) t += red[w];
    out[0] = t / (float)NROWS;
  }
}

extern "C" void kernel_launch(void* const* d_in, const int* in_sizes, int n_in,
                              void* d_out, int out_size, void* d_ws, size_t ws_size,
                              hipStream_t stream) {
  const float* zi = (const float*)d_in[0];
  const float* zj = (const float*)d_in[1];
  unsigned char* zn = (unsigned char*)d_ws;                           // 4 MB fp8
  float* sumexp = (float*)((char*)d_ws + (size_t)NROWS * DIM);        // 32 KB
  float* posv = sumexp + NROWS;                                       // 32 KB
  float* out = (float*)d_out;

  hipLaunchKernelGGL(k_normalize, dim3(2048), dim3(256), 0, stream, zi, zj, zn, sumexp);
  hipLaunchKernelGGL(k_simsum, dim3(NTILES), dim3(256), 0, stream, zn, sumexp, posv);
  hipLaunchKernelGGL(k_final, dim3(1), dim3(1024), 0, stream, sumexp, posv, out);
}